// Round 14
// baseline (119.561 us; speedup 1.0000x reference)
//
#include <hip/hip_runtime.h>
#include <hip/hip_bf16.h>
#include <stdint.h>

// y[c,k] = sum_{a,b} E1[k,a] * Xc[c,a,b] * E2[k,b],  Xc = C*x, E = exp(i*angle*g)
//
// R14: the R13 audit showed the gemm is LDS-BANDWIDTH-bound (216KB/CU/tile
// at ~98 B/cyc ~ the 112 B/cyc ceiling; explains why R5/R7/R9/R13 all tie and
// occupancy/barrier changes were null). The A round-trip (stage 32KB + read
// 32KB per block-tile) is 64KB of the 104KB — pure overhead, A rows are
// wave-private and read ONCE. So:
//  - A fragments load DIRECT global->VGPR from the packed image. The image
//    layout collapses to fully-coalesced 1KB per af load (8 x 128B runs),
//    no swizzle (that was for LDS banks). NO global_load_lds remains in the
//    K-loop -> vmcnt tracks only af loads -> compiler emits clean counted
//    waits (R2's hazard gone by construction). Unlike failed R6: 4-deep
//    load chains (not 16), 4 waves/SIMD (not 2), no vmcnt pollution.
//  - B stays computed-in-LDS (R10/R13 path, 1 sincos + 3 cmul per thread
//    per tile); et/t in 3 persistent VGPRs (etbuf LDS round-trip deleted).
//  - LDS = 2x4KB B dbuf + 4KB scol = 12KB. Regs cap occupancy at 2 blocks/CU.
//
// A content per (c,a): A_re row a     = [Re XcC[j] | -Im XcS[j]], j=1..128
//                      A_im row 256+a = [Im XcC[j] |  Re XcS[j]]
//   XcC[j]=Xc[128+j]+Xc[128-j], XcS[j]=Xc[128+j]-Xc[128-j] (j=1..127)
//   XcC[128]=Xc[b=0], XcS[128]=-Xc[b=0];  bias row = Xc[a,b=128] (g=0 term)

#define NKTOT 17408
#define NBLK 272    // ktiles of 64 k-values
#define NT 8        // K-tiles of 32 (K = 256 exactly)

typedef short bf16x8 __attribute__((ext_vector_type(8)));
typedef float f32x4 __attribute__((ext_vector_type(4)));

__device__ __forceinline__ unsigned short f2bf(float f) {
  unsigned int u = __builtin_bit_cast(unsigned int, f);
  u += 0x7FFFu + ((u >> 16) & 1u);
  return (unsigned short)(u >> 16);
}
__device__ __forceinline__ unsigned int pk2bf(float lo, float hi) {
  return (unsigned int)f2bf(lo) | ((unsigned int)f2bf(hi) << 16);
}

// A image: [c][tt<8][p<256][s<8][e<8] ushorts.
//   logical row m (0..511): p=m>>1 ; col jj (0..255): tt=jj>>5,
//   s=((m&1)<<2)|((jj>>3)&3), e=jj&7
__device__ __forceinline__ size_t aidx(int c, int m, int jj) {
  int tt = jj >> 5;
  int s = ((m & 1) << 2) | ((jj >> 3) & 3);
  return (((size_t)(c * 8 + tt) * 256 + (m >> 1)) * 8 + s) * 8 + (jj & 7);
}

// A fold + bias only (B/E1 computed inside gemm).
__global__ __launch_bounds__(256) void pack_a(
    const float* __restrict__ input_r, const float* __restrict__ C_r,
    unsigned short* __restrict__ Apack, float* __restrict__ biastab)
{
  const int bx = blockIdx.x;           // 0..1023
  const int tid = threadIdx.x;
  const int p = bx * 2 + (tid >> 7);   // (c,a) pair index 0..2047
  const int a = p & 255;
  const int c = p >> 8;
  const int j = tid & 127;
  const size_t xbase = (size_t)a * 256;
  const size_t cbase = ((size_t)(c * 256 + a)) * 256;
  if (j == 0) {
    // bias (b=128, g=0) and the unpaired b=0 (g=-128) fold
    float xr = input_r[(xbase + 128) * 2], xi = input_r[(xbase + 128) * 2 + 1];
    float cr = C_r[(cbase + 128) * 2],     ci = C_r[(cbase + 128) * 2 + 1];
    biastab[c * 512 + a]       = cr * xr - ci * xi;   // Re Xc[a,128]
    biastab[c * 512 + 256 + a] = cr * xi + ci * xr;   // Im Xc[a,128]
    xr = input_r[xbase * 2]; xi = input_r[xbase * 2 + 1];
    cr = C_r[cbase * 2];     ci = C_r[cbase * 2 + 1];
    float reb = cr * xr - ci * xi, imb = cr * xi + ci * xr;   // Xc[a,0]
    Apack[aidx(c, a, 127)]       = f2bf(reb);    // Re XcC[128]
    Apack[aidx(c, a, 255)]       = f2bf(imb);    // -Im XcS[128] = +Im Xc0
    Apack[aidx(c, 256 + a, 127)] = f2bf(imb);    // Im XcC[128]
    Apack[aidx(c, 256 + a, 255)] = f2bf(-reb);   // Re XcS[128] = -Re Xc0
  } else {
    const int bp = 128 + j, bm = 128 - j;
    float xpr = input_r[(xbase + bp) * 2], xpi = input_r[(xbase + bp) * 2 + 1];
    float cpr = C_r[(cbase + bp) * 2],     cpi = C_r[(cbase + bp) * 2 + 1];
    float pr = cpr * xpr - cpi * xpi, pi = cpr * xpi + cpi * xpr;
    float xmr = input_r[(xbase + bm) * 2], xmi = input_r[(xbase + bm) * 2 + 1];
    float cmr = C_r[(cbase + bm) * 2],     cmi = C_r[(cbase + bm) * 2 + 1];
    float mrv = cmr * xmr - cmi * xmi, miv = cmr * xmi + cmi * xmr;
    Apack[aidx(c, a, j - 1)]         = f2bf(pr + mrv);   //  Re XcC[j]
    Apack[aidx(c, a, 127 + j)]       = f2bf(miv - pi);   // -Im XcS[j]
    Apack[aidx(c, 256 + a, j - 1)]   = f2bf(pi + miv);   //  Im XcC[j]
    Apack[aidx(c, 256 + a, 127 + j)] = f2bf(pr - mrv);   //  Re XcS[j]
  }
}

// B tile for round `tile` into the swizzled LDS buffer. Thread (w,l):
// k-row kl=l, cols jl=w*4..+3; content col jj = tile*32+jl maps to
// trig(t*((tile&3)*32 + jl + 1)): cos (tiles 0-3) / sin (tiles 4-7).
// 1 sincos + chain by et = e^{it} (12 FMA). Layout: p=l>>1,
// s=((l&1)<<2)|(w>>1) stored at u=s^(p&7), halfword pair at (w&1)*4.
__device__ __forceinline__ void b_compute(unsigned short* buf, float2 et,
                                          float t, int tile, int w, int l,
                                          int bwoff) {
  const float jb = (float)((tile & 3) * 32 + w * 4 + 1);
  float s0, c0;
  __sincosf(t * jb, &s0, &c0);
  float c1 = c0 * et.x - s0 * et.y, s1 = s0 * et.x + c0 * et.y;
  float c2 = c1 * et.x - s1 * et.y, s2 = s1 * et.x + c1 * et.y;
  float c3 = c2 * et.x - s2 * et.y, s3 = s2 * et.x + c2 * et.y;
  const bool use_cos = tile < 4;
  float v0 = use_cos ? c0 : s0;
  float v1 = use_cos ? c1 : s1;
  float v2 = use_cos ? c2 : s2;
  float v3 = use_cos ? c3 : s3;
  uint2 pk;
  pk.x = pk2bf(v0, v1);
  pk.y = pk2bf(v2, v3);
  *(uint2*)(buf + bwoff) = pk;
}

__global__ __launch_bounds__(512, 4) void gemm_fused(
    const unsigned short* __restrict__ Apack,
    const float* __restrict__ biastab,
    const float* __restrict__ angle,
    const float* __restrict__ wvec,
    float* __restrict__ out)
{
  __shared__ unsigned short Bs[2][2048];   // 2 x 4 KB B double-buffer
  __shared__ float scol[8][2][64];         // 4 KB  => 12 KB total

  // XCD-aware decode: bx%8 == ktile%8. 2176 = 34*64 -> bijective.
  const int bx = blockIdx.x;
  const int c = (bx >> 3) & 7;
  const int ktile = (bx >> 6) * 8 + (bx & 7);   // 0..271
  const int kt0 = ktile * 64;
  const int tid = threadIdx.x;
  const int w = tid >> 6;       // 0..7: owns logical rows w*64..+63
  const int l = tid & 63;
  const int lhi = l >> 4;       // 0..3
  const int llo = l & 15;

  // Per-lane A base for DIRECT fragment loads. Lane (w,llo,lhi) needs
  // logical row m = w*64 + fi*16 + llo, cols jj = tt*32 + lhi*8..+7:
  //   ushort offset = (tt*256 + m>>1)*64 + (((llo&1)<<2)|lhi)*8   [+ fi*512]
  // Wave footprint per af load: 8 phys rows x 128 contiguous bytes = 1KB,
  // fully coalesced.
  const unsigned short* Alane = Apack + (size_t)c * (8 * 16384)
      + (size_t)(w * 32 + (llo >> 1)) * 64 + (((llo & 1) << 2) | lhi) * 8;
  const float* biasp = biastab + c * 512 + w * 64 + lhi * 4;

  // B fragment read: phys row p, content slot s=((llo&1)<<2)|lhi, u=s^(p&7)
  const int u8 = ((((llo & 1) << 2) | lhi) ^ ((llo >> 1) & 7)) * 8;
  const int plbase = llo >> 1;

  // per-thread B angle (k = kt0 + l) + chain constant e^{it} (persistent)
  const float t_reg = angle[(size_t)(kt0 + l) * 2 + 1];
  float2 et;
  __sincosf(t_reg, &et.y, &et.x);
  // B LDS write offset (same layout as R10/R13)
  const int bwoff = (l >> 1) * 64 +
      ((((l & 1) << 2) | (w >> 1)) ^ ((l >> 1) & 7)) * 8 + (w & 1) * 4;

  f32x4 acc[4][4];
  // acc init = bias (folded cos-col-0 rank-1 term; k-independent)
#pragma unroll
  for (int fi = 0; fi < 4; ++fi) {
    f32x4 b4 = *(const f32x4*)(biasp + fi * 16);
#pragma unroll
    for (int fj = 0; fj < 4; ++fj) acc[fi][fj] = b4;
  }

  // Prologue: emit B tile 0 (no A staging any more).
  b_compute(&Bs[0][0], et, t_reg, 0, w, l, bwoff);
  __syncthreads();

#pragma unroll 2
  for (int tt = 0; tt < NT; ++tt) {
    const int cu = tt & 1;
    // A fragments direct from global (4 x fully-coalesced dwordx4; the only
    // VMEM in the loop -> compiler emits counted vmcnt before their MFMAs).
    bf16x8 af[4];
#pragma unroll
    for (int fi = 0; fi < 4; ++fi)
      af[fi] = *(const bf16x8*)(Alane + (size_t)tt * 16384 + fi * 512);

    bf16x8 bfr[4];
#pragma unroll
    for (int fj = 0; fj < 4; ++fj)
      bfr[fj] = *(const bf16x8*)&Bs[cu][(fj * 8 + plbase) * 64 + u8];
#pragma unroll
    for (int fi = 0; fi < 4; ++fi)
#pragma unroll
      for (int fj = 0; fj < 4; ++fj)
        acc[fi][fj] = __builtin_amdgcn_mfma_f32_16x16x32_bf16(
            af[fi], bfr[fj], acc[fi][fj], 0, 0, 0);

    // Emit next B tile (VALU + one 8B ds_write; overlaps MFMA; consumed
    // after the barrier).
    if (tt < NT - 1)
      b_compute(&Bs[cu ^ 1][0], et, t_reg, tt + 1, w, l, bwoff);
    __syncthreads();
  }

  // Epilogue: wave w holds T rows m = w*64 + fi*16 + lhi*4 + r
  // (w<4: Tr, a=m; w>=4: Ti, a=m-256). E1 factored on the fly:
  //   S = e^{i s a0} * sum_fi e^{i 16 s fi} * (sum_r e^{i s r} v[fi][r]),
  //   a0 = (w&3)*64 + lhi*4 - 128, s = angle[k,0].
  const int aoff = (w & 3) * 64;
  const float a0f = (float)(aoff + lhi * 4 - 128);
#pragma unroll
  for (int fj = 0; fj < 4; ++fj) {
    const int col = fj * 16 + llo;
    const int k = kt0 + col;
    const float s = angle[(size_t)k * 2];
    float s1, c1, sY, cY;
    __sincosf(s, &s1, &c1);
    __sincosf(16.f * s, &sY, &cY);           // direct (R12-verified)
    float c2 = c1 * c1 - s1 * s1, s2 = 2.f * c1 * s1;
    float c3 = c2 * c1 - s2 * s1, s3 = c2 * s1 + s2 * c1;
    float cY2 = cY * cY - sY * sY, sY2 = 2.f * cY * sY;          // 32s
    float cY3 = cY2 * cY - sY2 * sY, sY3 = cY2 * sY + sY2 * cY;  // 48s
    const float Yr[4] = {1.f, cY, cY2, cY3};
    const float Yi[4] = {0.f, sY, sY2, sY3};
    float Or = 0.f, Oi = 0.f;
#pragma unroll
    for (int fi = 0; fi < 4; ++fi) {
      float v0 = acc[fi][fj][0], v1 = acc[fi][fj][1];
      float v2 = acc[fi][fj][2], v3 = acc[fi][fj][3];
      float Ir = v0 + c1 * v1 + c2 * v2 + c3 * v3;
      float Ii = s1 * v1 + s2 * v2 + s3 * v3;
      Or += Yr[fi] * Ir - Yi[fi] * Ii;
      Oi += Yi[fi] * Ir + Yr[fi] * Ii;
    }
    float sb, cb;
    __sincosf(s * a0f, &sb, &cb);
    float sumr = cb * Or - sb * Oi;
    float sumi = sb * Or + cb * Oi;
    sumr += __shfl_xor(sumr, 16, 64);
    sumr += __shfl_xor(sumr, 32, 64);
    sumi += __shfl_xor(sumi, 16, 64);
    sumi += __shfl_xor(sumi, 32, 64);
    if (lhi == 0) {
      scol[w][0][col] = sumr;
      scol[w][1][col] = sumi;
    }
  }
  __syncthreads();
  if (tid < 128) {
    const int col = tid >> 1;
    const int comp = tid & 1;
    const int k = kt0 + col;
    // Re = sum_{w<4} S_r(w) - sum_{w>=4} S_i(w)
    // Im = sum_{w<4} S_i(w) + sum_{w>=4} S_r(w)
    float re = scol[0][0][col] + scol[1][0][col] + scol[2][0][col] + scol[3][0][col]
             - scol[4][1][col] - scol[5][1][col] - scol[6][1][col] - scol[7][1][col];
    float im = scol[0][1][col] + scol[1][1][col] + scol[2][1][col] + scol[3][1][col]
             + scol[4][0][col] + scol[5][0][col] + scol[6][0][col] + scol[7][0][col];
    float val = comp ? im : re;
    out[((size_t)c * NKTOT + k) * 2 + comp] = val * wvec[k & 511];
  }
}

extern "C" void kernel_launch(void* const* d_in, const int* in_sizes, int n_in,
                              void* d_out, int out_size, void* d_ws, size_t ws_size,
                              hipStream_t stream) {
  const float* input_r = (const float*)d_in[0];  // (256,256,2)
  const float* C_r     = (const float*)d_in[1];  // (8,256,256,2)
  const float* wvec    = (const float*)d_in[2];  // (512,)
  const float* angle   = (const float*)d_in[3];  // (17408,2)
  float* out = (float*)d_out;                    // (8,17408,2)

  // workspace: Apack 2MB | biastab 16KB  => ~2.1MB
  unsigned short* Apack = (unsigned short*)d_ws;
  float* biastab = (float*)((char*)d_ws + (size_t)2097152);

  pack_a<<<1024, 256, 0, stream>>>(input_r, C_r, Apack, biastab);
  gemm_fused<<<8 * NBLK, 512, 0, stream>>>(Apack, biastab, angle, wvec, out);
}

// Round 15
// 113.125 us; speedup vs baseline: 1.0569x; 1.0569x over previous
//
#include <hip/hip_runtime.h>
#include <hip/hip_bf16.h>
#include <stdint.h>

// y[c,k] = sum_{a,b} E1[k,a] * Xc[c,a,b] * E2[k,b],  Xc = C*x, E = exp(i*angle*g)
//
// R15: kill the per-tile serialization. R10/R13/R14 all tie at ~63-65us with
// NO pipe >40% — the invariant is the per-tile 8-wave barrier + the serial
// chain {MFMA -> b_compute(sincos) -> ds_write -> barrier -> ds_read -> MFMA}.
// The whole B panel is only 32KB (64k x 256 cols bf16) -> compute ALL 8 B
// tiles in the PROLOGUE (8 sincos + 24 cmul per thread, once), ONE barrier,
// then a K-loop with ZERO barriers / ZERO LDS writes / ZERO gload_lds:
// per tile = 4 coalesced af global loads + 4 ds_read_b128 (static LDS) +
// 16 MFMA. Waves slide freely; compiler pipelines af loads with counted
// vmcnt (no gload_lds sharing the counter — R2/R8's hazard absent; 4
// waves/SIMD for TLP — R6's regime absent). In-loop trig: gone.
//  - LDS = 32KB B + 4KB scol = 36KB -> 2 blocks/CU.
//  - #pragma unroll 2 on the K-loop (spill guard; R4 lesson).
//
// A content per (c,a): A_re row a     = [Re XcC[j] | -Im XcS[j]], j=1..128
//                      A_im row 256+a = [Im XcC[j] |  Re XcS[j]]
//   XcC[j]=Xc[128+j]+Xc[128-j], XcS[j]=Xc[128+j]-Xc[128-j] (j=1..127)
//   XcC[128]=Xc[b=0], XcS[128]=-Xc[b=0];  bias row = Xc[a,b=128] (g=0 term)

#define NKTOT 17408
#define NBLK 272    // ktiles of 64 k-values
#define NT 8        // K-tiles of 32 (K = 256 exactly)

typedef short bf16x8 __attribute__((ext_vector_type(8)));
typedef float f32x4 __attribute__((ext_vector_type(4)));

__device__ __forceinline__ unsigned short f2bf(float f) {
  unsigned int u = __builtin_bit_cast(unsigned int, f);
  u += 0x7FFFu + ((u >> 16) & 1u);
  return (unsigned short)(u >> 16);
}
__device__ __forceinline__ unsigned int pk2bf(float lo, float hi) {
  return (unsigned int)f2bf(lo) | ((unsigned int)f2bf(hi) << 16);
}

// A image: [c][tt<8][p<256][s<8][e<8] ushorts.
//   logical row m (0..511): p=m>>1 ; col jj (0..255): tt=jj>>5,
//   s=((m&1)<<2)|((jj>>3)&3), e=jj&7
__device__ __forceinline__ size_t aidx(int c, int m, int jj) {
  int tt = jj >> 5;
  int s = ((m & 1) << 2) | ((jj >> 3) & 3);
  return (((size_t)(c * 8 + tt) * 256 + (m >> 1)) * 8 + s) * 8 + (jj & 7);
}

// A fold + bias only (B/E1 computed inside gemm).
__global__ __launch_bounds__(256) void pack_a(
    const float* __restrict__ input_r, const float* __restrict__ C_r,
    unsigned short* __restrict__ Apack, float* __restrict__ biastab)
{
  const int bx = blockIdx.x;           // 0..1023
  const int tid = threadIdx.x;
  const int p = bx * 2 + (tid >> 7);   // (c,a) pair index 0..2047
  const int a = p & 255;
  const int c = p >> 8;
  const int j = tid & 127;
  const size_t xbase = (size_t)a * 256;
  const size_t cbase = ((size_t)(c * 256 + a)) * 256;
  if (j == 0) {
    // bias (b=128, g=0) and the unpaired b=0 (g=-128) fold
    float xr = input_r[(xbase + 128) * 2], xi = input_r[(xbase + 128) * 2 + 1];
    float cr = C_r[(cbase + 128) * 2],     ci = C_r[(cbase + 128) * 2 + 1];
    biastab[c * 512 + a]       = cr * xr - ci * xi;   // Re Xc[a,128]
    biastab[c * 512 + 256 + a] = cr * xi + ci * xr;   // Im Xc[a,128]
    xr = input_r[xbase * 2]; xi = input_r[xbase * 2 + 1];
    cr = C_r[cbase * 2];     ci = C_r[cbase * 2 + 1];
    float reb = cr * xr - ci * xi, imb = cr * xi + ci * xr;   // Xc[a,0]
    Apack[aidx(c, a, 127)]       = f2bf(reb);    // Re XcC[128]
    Apack[aidx(c, a, 255)]       = f2bf(imb);    // -Im XcS[128] = +Im Xc0
    Apack[aidx(c, 256 + a, 127)] = f2bf(imb);    // Im XcC[128]
    Apack[aidx(c, 256 + a, 255)] = f2bf(-reb);   // Re XcS[128] = -Re Xc0
  } else {
    const int bp = 128 + j, bm = 128 - j;
    float xpr = input_r[(xbase + bp) * 2], xpi = input_r[(xbase + bp) * 2 + 1];
    float cpr = C_r[(cbase + bp) * 2],     cpi = C_r[(cbase + bp) * 2 + 1];
    float pr = cpr * xpr - cpi * xpi, pi = cpr * xpi + cpi * xpr;
    float xmr = input_r[(xbase + bm) * 2], xmi = input_r[(xbase + bm) * 2 + 1];
    float cmr = C_r[(cbase + bm) * 2],     cmi = C_r[(cbase + bm) * 2 + 1];
    float mrv = cmr * xmr - cmi * xmi, miv = cmr * xmi + cmi * xmr;
    Apack[aidx(c, a, j - 1)]         = f2bf(pr + mrv);   //  Re XcC[j]
    Apack[aidx(c, a, 127 + j)]       = f2bf(miv - pi);   // -Im XcS[j]
    Apack[aidx(c, 256 + a, j - 1)]   = f2bf(pi + miv);   //  Im XcC[j]
    Apack[aidx(c, 256 + a, 127 + j)] = f2bf(pr - mrv);   //  Re XcS[j]
  }
}

// B tile for round `tile` into the swizzled LDS buffer. Thread (w,l):
// k-row kl=l, cols jl=w*4..+3; content col jj = tile*32+jl maps to
// trig(t*((tile&3)*32 + jl + 1)): cos (tiles 0-3) / sin (tiles 4-7).
// 1 sincos + chain by et = e^{it} (12 FMA). Layout: p=l>>1,
// s=((l&1)<<2)|(w>>1) stored at u=s^(p&7), halfword pair at (w&1)*4.
__device__ __forceinline__ void b_compute(unsigned short* buf, float2 et,
                                          float t, int tile, int w, int l,
                                          int bwoff) {
  const float jb = (float)((tile & 3) * 32 + w * 4 + 1);
  float s0, c0;
  __sincosf(t * jb, &s0, &c0);
  float c1 = c0 * et.x - s0 * et.y, s1 = s0 * et.x + c0 * et.y;
  float c2 = c1 * et.x - s1 * et.y, s2 = s1 * et.x + c1 * et.y;
  float c3 = c2 * et.x - s2 * et.y, s3 = s2 * et.x + c2 * et.y;
  const bool use_cos = tile < 4;
  float v0 = use_cos ? c0 : s0;
  float v1 = use_cos ? c1 : s1;
  float v2 = use_cos ? c2 : s2;
  float v3 = use_cos ? c3 : s3;
  uint2 pk;
  pk.x = pk2bf(v0, v1);
  pk.y = pk2bf(v2, v3);
  *(uint2*)(buf + bwoff) = pk;
}

__global__ __launch_bounds__(512, 4) void gemm_fused(
    const unsigned short* __restrict__ Apack,
    const float* __restrict__ biastab,
    const float* __restrict__ angle,
    const float* __restrict__ wvec,
    float* __restrict__ out)
{
  __shared__ unsigned short Bs[8][2048];   // 32 KB: the ENTIRE B panel
  __shared__ float scol[8][2][64];         // 4 KB  => 36 KB -> 2 blocks/CU

  // XCD-aware decode: bx%8 == ktile%8. 2176 = 34*64 -> bijective.
  const int bx = blockIdx.x;
  const int c = (bx >> 3) & 7;
  const int ktile = (bx >> 6) * 8 + (bx & 7);   // 0..271
  const int kt0 = ktile * 64;
  const int tid = threadIdx.x;
  const int w = tid >> 6;       // 0..7: owns logical rows w*64..+63
  const int l = tid & 63;
  const int lhi = l >> 4;       // 0..3
  const int llo = l & 15;

  // Per-lane A base for DIRECT fragment loads (R14 layout: per af load the
  // wave touches 8 phys rows x 128 contiguous bytes = 1KB, fully coalesced).
  const unsigned short* Alane = Apack + (size_t)c * (8 * 16384)
      + (size_t)(w * 32 + (llo >> 1)) * 64 + (((llo & 1) << 2) | lhi) * 8;
  const float* biasp = biastab + c * 512 + w * 64 + lhi * 4;

  // B fragment read: phys row p, content slot s=((llo&1)<<2)|lhi, u=s^(p&7)
  const int u8 = ((((llo & 1) << 2) | lhi) ^ ((llo >> 1) & 7)) * 8;
  const int plbase = llo >> 1;

  // per-thread B angle (k = kt0 + l) + chain constant e^{it}
  const float t_reg = angle[(size_t)(kt0 + l) * 2 + 1];
  float2 et;
  __sincosf(t_reg, &et.y, &et.x);
  // B LDS write offset (same layout as R10/R13/R14)
  const int bwoff = (l >> 1) * 64 +
      ((((l & 1) << 2) | (w >> 1)) ^ ((l >> 1) & 7)) * 8 + (w & 1) * 4;

  f32x4 acc[4][4];
  // acc init = bias (folded cos-col-0 rank-1 term; k-independent)
#pragma unroll
  for (int fi = 0; fi < 4; ++fi) {
    f32x4 b4 = *(const f32x4*)(biasp + fi * 16);
#pragma unroll
    for (int fj = 0; fj < 4; ++fj) acc[fi][fj] = b4;
  }

  // Prologue: compute the ENTIRE B panel (8 tiles), then ONE barrier.
  // Trig state (et, transients) is prologue-only — no persistent regs.
#pragma unroll
  for (int tt = 0; tt < NT; ++tt)
    b_compute(&Bs[tt][0], et, t_reg, tt, w, l, bwoff);
  __syncthreads();

  // Barrier-free K-loop: pure {af global load, B ds_read, MFMA}. No LDS
  // writes, no gload_lds, no rendezvous — waves slide freely; compiler
  // pipelines af loads across iterations with counted vmcnt.
#pragma unroll 2
  for (int tt = 0; tt < NT; ++tt) {
    bf16x8 af[4];
#pragma unroll
    for (int fi = 0; fi < 4; ++fi)
      af[fi] = *(const bf16x8*)(Alane + (size_t)tt * 16384 + fi * 512);
    bf16x8 bfr[4];
#pragma unroll
    for (int fj = 0; fj < 4; ++fj)
      bfr[fj] = *(const bf16x8*)&Bs[tt][(fj * 8 + plbase) * 64 + u8];
#pragma unroll
    for (int fi = 0; fi < 4; ++fi)
#pragma unroll
      for (int fj = 0; fj < 4; ++fj)
        acc[fi][fj] = __builtin_amdgcn_mfma_f32_16x16x32_bf16(
            af[fi], bfr[fj], acc[fi][fj], 0, 0, 0);
  }

  // Epilogue: wave w holds T rows m = w*64 + fi*16 + lhi*4 + r
  // (w<4: Tr, a=m; w>=4: Ti, a=m-256). E1 factored on the fly:
  //   S = e^{i s a0} * sum_fi e^{i 16 s fi} * (sum_r e^{i s r} v[fi][r]),
  //   a0 = (w&3)*64 + lhi*4 - 128, s = angle[k,0].
  const int aoff = (w & 3) * 64;
  const float a0f = (float)(aoff + lhi * 4 - 128);
#pragma unroll
  for (int fj = 0; fj < 4; ++fj) {
    const int col = fj * 16 + llo;
    const int k = kt0 + col;
    const float s = angle[(size_t)k * 2];
    float s1, c1, sY, cY;
    __sincosf(s, &s1, &c1);
    __sincosf(16.f * s, &sY, &cY);           // direct (R12-verified)
    float c2 = c1 * c1 - s1 * s1, s2 = 2.f * c1 * s1;
    float c3 = c2 * c1 - s2 * s1, s3 = c2 * s1 + s2 * c1;
    float cY2 = cY * cY - sY * sY, sY2 = 2.f * cY * sY;          // 32s
    float cY3 = cY2 * cY - sY2 * sY, sY3 = cY2 * sY + sY2 * cY;  // 48s
    const float Yr[4] = {1.f, cY, cY2, cY3};
    const float Yi[4] = {0.f, sY, sY2, sY3};
    float Or = 0.f, Oi = 0.f;
#pragma unroll
    for (int fi = 0; fi < 4; ++fi) {
      float v0 = acc[fi][fj][0], v1 = acc[fi][fj][1];
      float v2 = acc[fi][fj][2], v3 = acc[fi][fj][3];
      float Ir = v0 + c1 * v1 + c2 * v2 + c3 * v3;
      float Ii = s1 * v1 + s2 * v2 + s3 * v3;
      Or += Yr[fi] * Ir - Yi[fi] * Ii;
      Oi += Yi[fi] * Ir + Yr[fi] * Ii;
    }
    float sb, cb;
    __sincosf(s * a0f, &sb, &cb);
    float sumr = cb * Or - sb * Oi;
    float sumi = sb * Or + cb * Oi;
    sumr += __shfl_xor(sumr, 16, 64);
    sumr += __shfl_xor(sumr, 32, 64);
    sumi += __shfl_xor(sumi, 16, 64);
    sumi += __shfl_xor(sumi, 32, 64);
    if (lhi == 0) {
      scol[w][0][col] = sumr;
      scol[w][1][col] = sumi;
    }
  }
  __syncthreads();
  if (tid < 128) {
    const int col = tid >> 1;
    const int comp = tid & 1;
    const int k = kt0 + col;
    // Re = sum_{w<4} S_r(w) - sum_{w>=4} S_i(w)
    // Im = sum_{w<4} S_i(w) + sum_{w>=4} S_r(w)
    float re = scol[0][0][col] + scol[1][0][col] + scol[2][0][col] + scol[3][0][col]
             - scol[4][1][col] - scol[5][1][col] - scol[6][1][col] - scol[7][1][col];
    float im = scol[0][1][col] + scol[1][1][col] + scol[2][1][col] + scol[3][1][col]
             + scol[4][0][col] + scol[5][0][col] + scol[6][0][col] + scol[7][0][col];
    float val = comp ? im : re;
    out[((size_t)c * NKTOT + k) * 2 + comp] = val * wvec[k & 511];
  }
}

extern "C" void kernel_launch(void* const* d_in, const int* in_sizes, int n_in,
                              void* d_out, int out_size, void* d_ws, size_t ws_size,
                              hipStream_t stream) {
  const float* input_r = (const float*)d_in[0];  // (256,256,2)
  const float* C_r     = (const float*)d_in[1];  // (8,256,256,2)
  const float* wvec    = (const float*)d_in[2];  // (512,)
  const float* angle   = (const float*)d_in[3];  // (17408,2)
  float* out = (float*)d_out;                    // (8,17408,2)

  // workspace: Apack 2MB | biastab 16KB  => ~2.1MB
  unsigned short* Apack = (unsigned short*)d_ws;
  float* biastab = (float*)((char*)d_ws + (size_t)2097152);

  pack_a<<<1024, 256, 0, stream>>>(input_r, C_r, Apack, biastab);
  gemm_fused<<<8 * NBLK, 512, 0, stream>>>(Apack, biastab, angle, wvec, out);
}